// Round 2
// baseline (107.757 us; speedup 1.0000x reference)
//
#include <hip/hip_runtime.h>
#include <hip/hip_bf16.h>

#ifndef __has_builtin
#define __has_builtin(x) 0
#endif

__device__ __forceinline__ float fast_exp2(float x) {
#if __has_builtin(__builtin_amdgcn_exp2f)
    return __builtin_amdgcn_exp2f(x);   // v_exp_f32
#else
    return exp2f(x);
#endif
}

__device__ __forceinline__ float fast_rcp(float x) {
#if __has_builtin(__builtin_amdgcn_rcpf)
    return __builtin_amdgcn_rcpf(x);    // v_rcp_f32, ~1 ulp — fine vs 6.8e-2 threshold
#else
    return 1.0f / x;
#endif
}

#define VQ_K   256
#define VQ_D   4
#define M_PER  8          // vectors per thread: amortizes the per-k LDS table read
#define BLK    256        // one table entry per thread in the init phase

// Single fused kernel (one dispatch — Round-1 showed ~53us of non-kernel time
// on the two-dispatch chain). Math: softmax weight for center k is
//   exp(-(|x|^2 - 2 x.c + |c|^2))  ∝  exp2(x . c2_k) * p_k,
// with c2 = 2*log2(e)*c and p_k = exp(-|c_k|^2); |x|^2 cancels in the ratio.
// Fold p into the acc operand (w = p*c) and the denominator operand (p), so
// the inner loop per (m,k) is: mul + 3 fma (dot) + v_exp + 5 fma = 9 main-pipe
// VALU + 1 trans. Table lives in LDS; reads are wave-uniform -> broadcast
// (conflict-free), one read set per k shared across M_PER=8 m's.
__global__ __launch_bounds__(BLK) void vq_fused(const float* __restrict__ x,
                                                const float* __restrict__ center,
                                                float* __restrict__ out) {
    __shared__ float4 sc2[VQ_K];   // 2*log2e * c_k
    __shared__ float4 sw [VQ_K];   // p_k * c_k
    __shared__ float  sp [VQ_K];   // p_k

    // ---- per-block table init: one k per thread ----
    {
        const float L2E = 1.4426950408889634f;
        int k = threadIdx.x;
        float4 c = reinterpret_cast<const float4*>(center)[k];
        float csq = c.x * c.x + c.y * c.y + c.z * c.z + c.w * c.w;
        float p = fast_exp2(-L2E * csq);            // exp(-|c|^2)
        float s = 2.0f * L2E;
        sc2[k] = make_float4(s * c.x, s * c.y, s * c.z, s * c.w);
        sw [k] = make_float4(p * c.x, p * c.y, p * c.z, p * c.w);
        sp [k] = p;
    }
    __syncthreads();

    // ---- main loop: 8 vectors per thread, coalesced (stride BLK float4s) ----
    const int base = blockIdx.x * (BLK * M_PER) + threadIdx.x;
    const float4* __restrict__ x4 = reinterpret_cast<const float4*>(x);

    float4 xv[M_PER];
#pragma unroll
    for (int j = 0; j < M_PER; ++j) xv[j] = x4[base + j * BLK];

    float4 acc[M_PER];
    float  den[M_PER];
#pragma unroll
    for (int j = 0; j < M_PER; ++j) {
        acc[j] = make_float4(0.f, 0.f, 0.f, 0.f);
        den[j] = 0.f;
    }

#pragma unroll 4
    for (int k = 0; k < VQ_K; ++k) {
        float4 c2 = sc2[k];
        float4 w  = sw [k];
        float  p  = sp [k];
#pragma unroll
        for (int j = 0; j < M_PER; ++j) {
            float t = xv[j].x * c2.x;
            t = fmaf(xv[j].y, c2.y, t);
            t = fmaf(xv[j].z, c2.z, t);
            t = fmaf(xv[j].w, c2.w, t);
            float e = fast_exp2(t);                 // exp(2 x.c_k)
            den[j]   = fmaf(e, p,   den[j]);
            acc[j].x = fmaf(e, w.x, acc[j].x);
            acc[j].y = fmaf(e, w.y, acc[j].y);
            acc[j].z = fmaf(e, w.z, acc[j].z);
            acc[j].w = fmaf(e, w.w, acc[j].w);
        }
    }

    float4* __restrict__ o4 = reinterpret_cast<float4*>(out);
#pragma unroll
    for (int j = 0; j < M_PER; ++j) {
        float inv = fast_rcp(den[j]);
        float4 o;
        o.x = acc[j].x * inv;
        o.y = acc[j].y * inv;
        o.z = acc[j].z * inv;
        o.w = acc[j].w * inv;
        o4[base + j * BLK] = o;
    }
}

extern "C" void kernel_launch(void* const* d_in, const int* in_sizes, int n_in,
                              void* d_out, int out_size, void* d_ws, size_t ws_size,
                              hipStream_t stream) {
    const float* x      = (const float*)d_in[0];   // [8, 262144] fp32
    const float* center = (const float*)d_in[1];   // [256, 4] fp32
    float* out = (float*)d_out;

    int nvec   = in_sizes[0] / VQ_D;               // 524288
    int blocks = nvec / (BLK * M_PER);             // 256
    vq_fused<<<blocks, BLK, 0, stream>>>(x, center, out);
}

// Round 3
// 93.740 us; speedup vs baseline: 1.1495x; 1.1495x over previous
//
#include <hip/hip_runtime.h>
#include <hip/hip_bf16.h>

#ifndef __has_builtin
#define __has_builtin(x) 0
#endif

__device__ __forceinline__ float fast_exp2(float x) {
#if __has_builtin(__builtin_amdgcn_exp2f)
    return __builtin_amdgcn_exp2f(x);   // v_exp_f32
#else
    return exp2f(x);
#endif
}

__device__ __forceinline__ float fast_rcp(float x) {
#if __has_builtin(__builtin_amdgcn_rcpf)
    return __builtin_amdgcn_rcpf(x);    // v_rcp_f32; fine vs 6.8e-2 threshold
#else
    return 1.0f / x;
#endif
}

#define VQ_K    256
#define VQ_D    4
#define M_PER   8      // m-vectors per lane (amortizes table reads over DS pipe)
#define KSPLIT  4      // lane-groups per wave: sub = lane>>4 owns K/4 centers
#define BLK     256
// Each wave: 16 lanes x M_PER = 128 m's, replicated across 4 k-subgroups.
// waves = 524288*KSPLIT/(64*M_PER) = 4096 -> 4 waves/SIMD (fixes R2's 1/SIMD).

// Table row k (8 floats): [c2.x c2.y c2.z c2.w | c.x c.y c.z b]
//   c2 = 2*log2e * c_k ; b = -log2e*|c_k|^2 (p folded into exponent);
//   c.w reconstructed as c2.w * (ln2/2). Softmax weight = exp2(x.c2 + b),
//   |x|^2 cancels in acc/den ratio. Rows staggered +4 floats per k-subgroup
//   so the 4 distinct ds_read addresses per wave hit disjoint bank quads.
#define GRP_STRIDE 516   // floats per k-subgroup region: 64*8 + 4 stagger

__global__ __launch_bounds__(BLK, 4) void vq_fused(const float* __restrict__ x,
                                                   const float* __restrict__ center,
                                                   float* __restrict__ out) {
    __shared__ float tbl[KSPLIT * GRP_STRIDE];   // 8256 B

    // ---- table init: one k per thread ----
    {
        const float L2E = 1.4426950408889634f;
        int k = threadIdx.x;
        float4 c = reinterpret_cast<const float4*>(center)[k];
        float csq = c.x * c.x + c.y * c.y + c.z * c.z + c.w * c.w;
        float b = -L2E * csq;
        float s = 2.0f * L2E;
        int off = (k >> 6) * GRP_STRIDE + (k & 63) * 8;
        float4* row = reinterpret_cast<float4*>(tbl + off);
        row[0] = make_float4(s * c.x, s * c.y, s * c.z, s * c.w);
        row[1] = make_float4(c.x, c.y, c.z, b);
    }
    __syncthreads();

    const int lane  = threadIdx.x & 63;
    const int wid   = threadIdx.x >> 6;          // wave in block (0..3)
    const int sub   = lane >> 4;                 // k-subgroup (0..3)
    const int mlane = lane & 15;                 // m-lane within subgroup

    // wave handles 128 consecutive m's; block (4 waves) handles 512
    const int mbase = blockIdx.x * (4 * 16 * M_PER) + wid * (16 * M_PER) + mlane;
    const float4* __restrict__ x4 = reinterpret_cast<const float4*>(x);

    float4 xv[M_PER];
#pragma unroll
    for (int j = 0; j < M_PER; ++j) xv[j] = x4[mbase + j * 16];

    float4 acc[M_PER];
    float  den[M_PER];
#pragma unroll
    for (int j = 0; j < M_PER; ++j) {
        acc[j] = make_float4(0.f, 0.f, 0.f, 0.f);
        den[j] = 0.f;
    }

    const float4* __restrict__ tb =
        reinterpret_cast<const float4*>(tbl + sub * GRP_STRIDE);
    const float HALF_LN2 = 0.34657359027997264f;   // ln2/2 = 1/(2*log2e)

#pragma unroll 4
    for (int i = 0; i < VQ_K / KSPLIT; ++i) {      // 64 iters over this sub's k's
        float4 c2 = tb[i * 2];                     // ds_read_b128
        float4 cb = tb[i * 2 + 1];                 // c.xyz, b
        float  cw = c2.w * HALF_LN2;               // reconstruct c.w
#pragma unroll
        for (int j = 0; j < M_PER; ++j) {
            float t = fmaf(xv[j].x, c2.x, cb.w);   // bias-folded exponent
            t = fmaf(xv[j].y, c2.y, t);
            t = fmaf(xv[j].z, c2.z, t);
            t = fmaf(xv[j].w, c2.w, t);
            float e = fast_exp2(t);
            den[j]  += e;
            acc[j].x = fmaf(e, cb.x, acc[j].x);
            acc[j].y = fmaf(e, cb.y, acc[j].y);
            acc[j].z = fmaf(e, cb.z, acc[j].z);
            acc[j].w = fmaf(e, cw,   acc[j].w);
        }
    }

    // ---- combine the 4 k-subgroups: butterfly over lane bits 4,5 ----
#pragma unroll
    for (int j = 0; j < M_PER; ++j) {
        den[j]   += __shfl_xor(den[j],   16, 64);
        acc[j].x += __shfl_xor(acc[j].x, 16, 64);
        acc[j].y += __shfl_xor(acc[j].y, 16, 64);
        acc[j].z += __shfl_xor(acc[j].z, 16, 64);
        acc[j].w += __shfl_xor(acc[j].w, 16, 64);
        den[j]   += __shfl_xor(den[j],   32, 64);
        acc[j].x += __shfl_xor(acc[j].x, 32, 64);
        acc[j].y += __shfl_xor(acc[j].y, 32, 64);
        acc[j].z += __shfl_xor(acc[j].z, 32, 64);
        acc[j].w += __shfl_xor(acc[j].w, 32, 64);
    }

    if (sub == 0) {
        float4* __restrict__ o4 = reinterpret_cast<float4*>(out);
#pragma unroll
        for (int j = 0; j < M_PER; ++j) {
            float inv = fast_rcp(den[j]);
            float4 o;
            o.x = acc[j].x * inv;
            o.y = acc[j].y * inv;
            o.z = acc[j].z * inv;
            o.w = acc[j].w * inv;
            o4[mbase + j * 16] = o;
        }
    }
}

extern "C" void kernel_launch(void* const* d_in, const int* in_sizes, int n_in,
                              void* d_out, int out_size, void* d_ws, size_t ws_size,
                              hipStream_t stream) {
    const float* x      = (const float*)d_in[0];   // [8, 262144] fp32
    const float* center = (const float*)d_in[1];   // [256, 4] fp32
    float* out = (float*)d_out;

    int nvec   = in_sizes[0] / VQ_D;               // 524288 m-vectors
    int blocks = nvec / (4 * 16 * M_PER);          // 1024 blocks (512 m each)
    vq_fused<<<blocks, BLK, 0, stream>>>(x, center, out);
}

// Round 4
// 89.285 us; speedup vs baseline: 1.2069x; 1.0499x over previous
//
#include <hip/hip_runtime.h>
#include <hip/hip_bf16.h>

#ifndef __has_builtin
#define __has_builtin(x) 0
#endif

typedef float f2 __attribute__((ext_vector_type(2)));

__device__ __forceinline__ float fast_exp2(float x) {
#if __has_builtin(__builtin_amdgcn_exp2f)
    return __builtin_amdgcn_exp2f(x);   // v_exp_f32 (trans pipe, ~16 issue cyc/wave)
#else
    return exp2f(x);
#endif
}

__device__ __forceinline__ float fast_rcp(float x) {
#if __has_builtin(__builtin_amdgcn_rcpf)
    return __builtin_amdgcn_rcpf(x);
#else
    return 1.0f / x;
#endif
}

// ---- packed fp32 helpers (VOP3P). op_sel/op_sel_hi broadcast one half of a
// source pair into both result halves -> scalar-broadcast operands are free.
__device__ __forceinline__ f2 pk_fma(f2 a, f2 b, f2 c) {           // elementwise
    f2 d;
    asm("v_pk_fma_f32 %0, %1, %2, %3" : "=v"(d) : "v"(a), "v"(b), "v"(c));
    return d;
}
__device__ __forceinline__ f2 pk_fma_b0(f2 a, f2 b, f2 c) {        // a*bcast(b.lo)+c
    f2 d;
    asm("v_pk_fma_f32 %0, %1, %2, %3 op_sel_hi:[1,0,1]"
        : "=v"(d) : "v"(a), "v"(b), "v"(c));
    return d;
}
__device__ __forceinline__ f2 pk_fma_b1(f2 a, f2 b, f2 c) {        // a*bcast(b.hi)+c
    f2 d;
    asm("v_pk_fma_f32 %0, %1, %2, %3 op_sel:[0,1,0] op_sel_hi:[1,1,1]"
        : "=v"(d) : "v"(a), "v"(b), "v"(c));
    return d;
}
__device__ __forceinline__ f2 pk_mul_b1(f2 a, f2 b) {              // a*bcast(b.hi)
    f2 d;
    asm("v_pk_mul_f32 %0, %1, %2 op_sel:[0,1] op_sel_hi:[1,1]"
        : "=v"(d) : "v"(a), "v"(b));
    return d;
}
__device__ __forceinline__ f2 pk_add(f2 a, f2 b) {
    f2 d;
    asm("v_pk_add_f32 %0, %1, %2" : "=v"(d) : "v"(a), "v"(b));
    return d;
}
__device__ __forceinline__ f2 shfl2(f2 a, int m) {
    f2 r;
    r.x = __shfl_xor(a.x, m, 64);
    r.y = __shfl_xor(a.y, m, 64);
    return r;
}

#define VQ_K    256
#define VQ_D    4
#define M_PER   8      // m-vectors per lane = 4 packed pairs
#define KSPLIT  4      // lane-groups of 16; sub = lane>>4 owns K/4 centers
#define BLK     256
#define GRP_STRIDE 516 // floats per k-subgroup region: 64*8 + 4 stagger

// Softmax weight = exp2(x.c2 + b), c2 = 2*log2e*c, b = -log2e*|c|^2; |x|^2
// cancels in acc/den. Inner math packed 2-m-per-inst via v_pk_fma_f32; table
// scalars broadcast from LDS-loaded pairs via op_sel (zero dup movs).
// Per wave-k-iter: 2 setup pk + 4 pairs x (4 dot pk + 1 pk_add + 4 acc pk)
// = 38 main-pipe + 8 v_exp.
__global__ __launch_bounds__(BLK, 4) void vq_fused(const float* __restrict__ x,
                                                   const float* __restrict__ center,
                                                   float* __restrict__ out) {
    __shared__ float tbl[KSPLIT * GRP_STRIDE];   // 8256 B

    // ---- table init: one k per thread ----
    {
        const float L2E = 1.4426950408889634f;
        int k = threadIdx.x;
        float4 c = reinterpret_cast<const float4*>(center)[k];
        float csq = c.x * c.x + c.y * c.y + c.z * c.z + c.w * c.w;
        float b = -L2E * csq;
        float s = 2.0f * L2E;
        int off = (k >> 6) * GRP_STRIDE + (k & 63) * 8;
        float4* row = reinterpret_cast<float4*>(tbl + off);
        row[0] = make_float4(s * c.x, s * c.y, s * c.z, s * c.w);  // c2
        row[1] = make_float4(c.x, c.y, c.z, b);                    // c.xyz, bias
    }
    __syncthreads();

    const int lane  = threadIdx.x & 63;
    const int wid   = threadIdx.x >> 6;
    const int sub   = lane >> 4;                 // k-subgroup (0..3)
    const int mlane = lane & 15;

    const int mbase = blockIdx.x * (4 * 16 * M_PER) + wid * (16 * M_PER) + mlane;
    const float4* __restrict__ x4 = reinterpret_cast<const float4*>(x);

    // load 8 vectors, repack into m-pairs: xp*[p] = {x_{2p}.d, x_{2p+1}.d}
    f2 xpx[4], xpy[4], xpz[4], xpw[4];
#pragma unroll
    for (int p = 0; p < 4; ++p) {
        float4 a = x4[mbase + (2 * p)     * 16];
        float4 b = x4[mbase + (2 * p + 1) * 16];
        xpx[p] = f2{a.x, b.x};
        xpy[p] = f2{a.y, b.y};
        xpz[p] = f2{a.z, b.z};
        xpw[p] = f2{a.w, b.w};
    }

    f2 ax[4], ay[4], az[4], aw[4], dn[4];
#pragma unroll
    for (int p = 0; p < 4; ++p) {
        ax[p] = f2{0.f, 0.f}; ay[p] = f2{0.f, 0.f};
        az[p] = f2{0.f, 0.f}; aw[p] = f2{0.f, 0.f};
        dn[p] = f2{0.f, 0.f};
    }

    const f2* __restrict__ tb2 = reinterpret_cast<const f2*>(tbl + sub * GRP_STRIDE);
    const f2 H2   = f2{0.34657359027997264f, 0.34657359027997264f};  // ln2/2
    const f2 ONE2 = f2{1.0f, 1.0f};

#pragma unroll 2
    for (int i = 0; i < VQ_K / KSPLIT; ++i) {     // 64 k's for this subgroup
        f2 c2xy = tb2[i * 4 + 0];                 // {c2.x, c2.y}
        f2 c2zw = tb2[i * 4 + 1];                 // {c2.z, c2.w}
        f2 cbxy = tb2[i * 4 + 2];                 // {c.x,  c.y }
        f2 cbzw = tb2[i * 4 + 3];                 // {c.z,  b   }
        f2 b2  = pk_mul_b1(ONE2, cbzw);           // {b, b}
        f2 cw2 = pk_mul_b1(H2,   c2zw);           // {c.w, c.w}
#pragma unroll
        for (int p = 0; p < 4; ++p) {
            f2 t = pk_fma_b0(xpx[p], c2xy, b2);   // x.x*c2.x + b
            t = pk_fma_b1(xpy[p], c2xy, t);       // + x.y*c2.y
            t = pk_fma_b0(xpz[p], c2zw, t);       // + x.z*c2.z
            t = pk_fma_b1(xpw[p], c2zw, t);       // + x.w*c2.w
            f2 e;
            e.x = fast_exp2(t.x);
            e.y = fast_exp2(t.y);
            dn[p] = pk_add(dn[p], e);
            ax[p] = pk_fma_b0(e, cbxy, ax[p]);
            ay[p] = pk_fma_b1(e, cbxy, ay[p]);
            az[p] = pk_fma_b0(e, cbzw, az[p]);
            aw[p] = pk_fma(e, cw2, aw[p]);
        }
    }

    // ---- combine 4 k-subgroups across lane bits 4,5 ----
#pragma unroll
    for (int p = 0; p < 4; ++p) {
        dn[p] = pk_add(dn[p], shfl2(dn[p], 16));
        ax[p] = pk_add(ax[p], shfl2(ax[p], 16));
        ay[p] = pk_add(ay[p], shfl2(ay[p], 16));
        az[p] = pk_add(az[p], shfl2(az[p], 16));
        aw[p] = pk_add(aw[p], shfl2(aw[p], 16));
        dn[p] = pk_add(dn[p], shfl2(dn[p], 32));
        ax[p] = pk_add(ax[p], shfl2(ax[p], 32));
        ay[p] = pk_add(ay[p], shfl2(ay[p], 32));
        az[p] = pk_add(az[p], shfl2(az[p], 32));
        aw[p] = pk_add(aw[p], shfl2(aw[p], 32));
    }

    if (sub == 0) {
        float4* __restrict__ o4 = reinterpret_cast<float4*>(out);
#pragma unroll
        for (int p = 0; p < 4; ++p) {
            float i0 = fast_rcp(dn[p].x);
            float i1 = fast_rcp(dn[p].y);
            float4 o0, o1;
            o0.x = ax[p].x * i0; o0.y = ay[p].x * i0;
            o0.z = az[p].x * i0; o0.w = aw[p].x * i0;
            o1.x = ax[p].y * i1; o1.y = ay[p].y * i1;
            o1.z = az[p].y * i1; o1.w = aw[p].y * i1;
            o4[mbase + (2 * p)     * 16] = o0;
            o4[mbase + (2 * p + 1) * 16] = o1;
        }
    }
}

extern "C" void kernel_launch(void* const* d_in, const int* in_sizes, int n_in,
                              void* d_out, int out_size, void* d_ws, size_t ws_size,
                              hipStream_t stream) {
    const float* x      = (const float*)d_in[0];   // [8, 262144] fp32
    const float* center = (const float*)d_in[1];   // [256, 4] fp32
    float* out = (float*)d_out;

    int nvec   = in_sizes[0] / VQ_D;               // 524288 m-vectors
    int blocks = nvec / (4 * 16 * M_PER);          // 1024
    vq_fused<<<blocks, BLK, 0, stream>>>(x, center, out);
}